// Round 8
// baseline (239.587 us; speedup 1.0000x reference)
//
#include <hip/hip_runtime.h>
#include <math.h>
#include <stdint.h>

// B=8, S=2048, D=512 single-head self-attention, fp32 in/out, fp16 MFMA inside.
// Round 8 = round-7 (226us) with the K-loop restructured as a software
// pipeline: double-buffered 32-half stages, ONE barrier per stage, loads for
// stage s+1 issued before computing stage s -> the vmcnt(0) drain at the next
// barrier finds them already complete (r7 evidence: 45% stall cycles from
// exposed DMA latency; memory traffic was already fixed by the XCD pin).
//
//  1. prep:        Xh = fp16(x);  W*T = fp16(W^T) for q,k,v
//  2. proj_mfma:   z=0: Qh = (Xh.Wq + bq)/sqrt(512)   z=1: Kh = Xh.Wk + bk
//                  z=2: Vt[b][d][s] = (Xh.Wv + bv)^T  (direct transposed GEMM)
//  3. scores_mfma: P[b] = fp16(exp(Qh.Kh^T))  UNNORMALIZED (scores ~N(0,1),
//                  exp<=~300 in fp16; verified r3-r7, absmax 2e-3)
//  4. av_mfma:     out[b] = (P.V) * mask[row] / l[row]; l = rowsum(P) via
//                  in-K-loop dot-with-ones (r5 win).
//
// Staging slab = 128 rows x 32 halves (8KB), 8 chunks of 1KB (16 rows x 64B),
// wave w fills chunks 2w,2w+1. Swizzle: 16B chunk c of row r stored at
// c ^ ((r ^ (r>>2)) & 3); applied in DMA source addr (permutes within 64B
// rows -> coalesced) and fragment reads. Bank analysis: 2 lanes/bank-group
// per 16-lane phase = free (2-way, m136). Two slab pairs = 32KB total.

typedef _Float16 f16x8 __attribute__((ext_vector_type(8)));
typedef _Float16 f16x4 __attribute__((ext_vector_type(4)));
typedef _Float16 f16x2 __attribute__((ext_vector_type(2)));
typedef float f32x4 __attribute__((ext_vector_type(4)));

__device__ __forceinline__ void async16(const _Float16* g, _Float16* l) {
    __builtin_amdgcn_global_load_lds(
        (const __attribute__((address_space(1))) unsigned int*)(uintptr_t)g,
        (__attribute__((address_space(3))) unsigned int*)(unsigned int)(uintptr_t)l,
        16, 0, 0);
}

__device__ __forceinline__ float frag_sum8(f16x8 v, float acc) {
#if __has_builtin(__builtin_amdgcn_fdot2)
    const f16x2 one2 = {(_Float16)1.f, (_Float16)1.f};
    const f16x2* p = (const f16x2*)&v;
    acc = __builtin_amdgcn_fdot2(p[0], one2, acc, false);
    acc = __builtin_amdgcn_fdot2(p[1], one2, acc, false);
    acc = __builtin_amdgcn_fdot2(p[2], one2, acc, false);
    acc = __builtin_amdgcn_fdot2(p[3], one2, acc, false);
#else
#pragma unroll
    for (int j = 0; j < 8; j++) acc += (float)v[j];
#endif
    return acc;
}

// acc[4][4] += A[row0:+128][0:K] . B[col0:+128][0:K]^T ; A:[M][K] B:[N][K].
// sm: 4 slabs of 4096 halves: As0 | Bs0 | As1 | Bs1 (32KB).
template <bool WITH_RS>
__device__ __forceinline__ void mfma_gemm_dbuf(
    const _Float16* __restrict__ A, int lda,
    const _Float16* __restrict__ B, int ldb,
    int K, int row0, int col0,
    _Float16* sm, f32x4 acc[4][4], float rs[4])
{
    const int tid  = threadIdx.x;
    const int lane = tid & 63;
    const int wave = tid >> 6;
    const int wm   = wave >> 1, wn = wave & 1;

    // staging: lane -> (row-in-chunk, swizzled 16B col)
    const int rL  = lane >> 2;
    const int key = ((lane >> 2) ^ (lane >> 4)) & 3;
    const int cs  = ((lane & 3) ^ key) * 8;

    const _Float16* gA0 = A + (size_t)(row0 + wave * 32      + rL) * lda + cs;
    const _Float16* gA1 = A + (size_t)(row0 + wave * 32 + 16 + rL) * lda + cs;
    const _Float16* gB0 = B + (size_t)(col0 + wave * 32      + rL) * ldb + cs;
    const _Float16* gB1 = B + (size_t)(col0 + wave * 32 + 16 + rL) * ldb + cs;

    // fragment read: row fr, k-chunk q, swizzle key kf = (fr ^ fr>>2) & 3
    const int fr = lane & 15;
    const int q  = lane >> 4;
    const int kc = ((q ^ ((fr ^ (fr >> 2)) & 3))) * 8;

    const int S = K >> 5;                    // 32-half stages

    // prologue: stage 0 -> buf 0
    async16(gA0, sm +        wave * 1024);
    async16(gA1, sm +        wave * 1024 + 512);
    async16(gB0, sm + 4096 + wave * 1024);
    async16(gB1, sm + 4096 + wave * 1024 + 512);

#pragma unroll 2
    for (int s = 0; s < S; s++) {
        __syncthreads();                     // drains stage-s loads (issued
                                             // one full compute phase ago)
        if (s + 1 < S) {
            int k = (s + 1) << 5;
            _Float16* dA = sm + ((s + 1) & 1) * 8192;
            _Float16* dB = dA + 4096;
            async16(gA0 + k, dA + wave * 1024);
            async16(gA1 + k, dA + wave * 1024 + 512);
            async16(gB0 + k, dB + wave * 1024);
            async16(gB1 + k, dB + wave * 1024 + 512);
        }
        const _Float16* As = sm + (s & 1) * 8192;
        const _Float16* Bs = As + 4096;
        f16x8 af[4], bf[4];
#pragma unroll
        for (int t = 0; t < 4; t++) {
            af[t] = *(const f16x8*)&As[(wm * 64 + t * 16 + fr) * 32 + kc];
            bf[t] = *(const f16x8*)&Bs[(wn * 64 + t * 16 + fr) * 32 + kc];
        }
        if (WITH_RS) {
#pragma unroll
            for (int t = 0; t < 4; t++) rs[t] = frag_sum8(af[t], rs[t]);
        }
#pragma unroll
        for (int tm = 0; tm < 4; tm++)
#pragma unroll
            for (int tn = 0; tn < 4; tn++)
                acc[tm][tn] = __builtin_amdgcn_mfma_f32_16x16x32_f16(
                    af[tm], bf[tn], acc[tm][tn], 0, 0, 0);
    }
}

// ---------------- 1. prep: x->fp16 and W->fp16 W^T --------------------------
__global__ __launch_bounds__(256) void prep(
    const float* __restrict__ x,
    const float* __restrict__ Wq, const float* __restrict__ Wk,
    const float* __restrict__ Wv,
    _Float16* __restrict__ Xh,
    _Float16* __restrict__ WqT, _Float16* __restrict__ WkT,
    _Float16* __restrict__ WvT)
{
    const int bid = blockIdx.x;
    if (bid < 8192) {                       // convert x
        int i = (bid * 256 + threadIdx.x) * 4;
        float4 v = *(const float4*)(x + i);
        f16x4 h;
        h.x = (_Float16)v.x; h.y = (_Float16)v.y;
        h.z = (_Float16)v.z; h.w = (_Float16)v.w;
        *(f16x4*)&Xh[i] = h;
    } else {                                // transpose W
        int t = bid - 8192;
        int z = t >> 10;
        const float* W = (z == 0) ? Wq : (z == 1) ? Wk : Wv;
        _Float16* Wt   = (z == 0) ? WqT : (z == 1) ? WkT : WvT;
        int idx = (t & 1023) * 256 + threadIdx.x;
        int n = idx >> 9, k = idx & 511;
        Wt[idx] = (_Float16)W[k * 512 + n];
    }
}

// ---------------- 2. projections --------------------------------------------
// grid (x=128 X-row-tiles, y=4 W-cols, z=3): same X row-tile across y -> bids
// differ by 128 (=0 mod 8) -> same XCD -> X rows served from its L2.
__global__ __launch_bounds__(256) void proj_mfma(
    const _Float16* __restrict__ Xh,
    const _Float16* __restrict__ WqT, const float* __restrict__ bq,
    const _Float16* __restrict__ WkT, const float* __restrict__ bk,
    const _Float16* __restrict__ WvT, const float* __restrict__ bv,
    _Float16* __restrict__ Qh, _Float16* __restrict__ Kh,
    _Float16* __restrict__ Vt)
{
    __shared__ __align__(16) _Float16 smem[16384];

    const int z = blockIdx.z;
    f32x4 acc[4][4];
#pragma unroll
    for (int i = 0; i < 4; i++)
#pragma unroll
        for (int j = 0; j < 4; j++) acc[i][j] = (f32x4){0.f, 0.f, 0.f, 0.f};
    float rs_unused[4];

    const int lane = threadIdx.x & 63, wave = threadIdx.x >> 6;
    const int wm = wave >> 1, wn = wave & 1;
    const int er = (lane >> 4) * 4, ec = lane & 15;  // C/D: col=lane&15, row=q*4+reg

    if (z < 2) {
        const _Float16* Wt = (z == 0) ? WqT : WkT;
        const float* bias  = (z == 0) ? bq : bk;
        _Float16* P        = (z == 0) ? Qh : Kh;
        const float sc     = (z == 0) ? 0.04419417382415922f : 1.0f;
        const int row0 = blockIdx.x * 128, col0 = blockIdx.y * 128;
        mfma_gemm_dbuf<false>(Xh, 512, Wt, 512, 512, row0, col0, smem, acc,
                              rs_unused);
#pragma unroll
        for (int tm = 0; tm < 4; tm++)
#pragma unroll
            for (int tn = 0; tn < 4; tn++) {
                int col = col0 + wn * 64 + tn * 16 + ec;
                float bb = bias[col];
#pragma unroll
                for (int r = 0; r < 4; r++) {
                    int row = row0 + wm * 64 + tm * 16 + er + r;
                    P[(size_t)row * 512 + col] = (_Float16)((acc[tm][tn][r] + bb) * sc);
                }
            }
    } else {
        // transposed V: out(row=d, col=s_global) = sum_k WvT[d][k] * Xh[s][k]
        const int row0 = blockIdx.y * 128;   // d (M=512)
        const int col0 = blockIdx.x * 128;   // s_global (N=16384)
        mfma_gemm_dbuf<false>(WvT, 512, Xh, 512, 512, row0, col0, smem, acc,
                              rs_unused);
#pragma unroll
        for (int tm = 0; tm < 4; tm++)
#pragma unroll
            for (int tn = 0; tn < 4; tn++) {
                int col = col0 + wn * 64 + tn * 16 + ec;   // s_global
                size_t obase = (size_t)(col >> 11) * (512 * 2048) + (col & 2047);
#pragma unroll
                for (int r = 0; r < 4; r++) {
                    int row = row0 + wm * 64 + tm * 16 + er + r;  // d
                    Vt[obase + (size_t)row * 2048] = (_Float16)(acc[tm][tn][r] + bv[row]);
                }
            }
    }
}

// ---------------- 3. scores: P = exp(Q.K^T) (unnormalized) ------------------
// 1-D grid 2048: batch = bid&7 (XCD pin: Q[b]+K[b]=4MB=one XCD L2), col fast.
__global__ __launch_bounds__(256) void scores_mfma(
    const _Float16* __restrict__ Qh, const _Float16* __restrict__ Kh,
    _Float16* __restrict__ Sh)
{
    __shared__ __align__(16) _Float16 smem[16384];
    const int bid = blockIdx.x;
    const int b   = bid & 7;
    const int rem = bid >> 3;
    const int col0 = (rem & 15) * 128;
    const int row0 = (rem >> 4) * 128;

    const _Float16* A = Qh + (size_t)b * 2048 * 512;
    const _Float16* B = Kh + (size_t)b * 2048 * 512;
    _Float16* S = Sh + (size_t)b * 2048 * 2048;

    f32x4 acc[4][4];
#pragma unroll
    for (int i = 0; i < 4; i++)
#pragma unroll
        for (int j = 0; j < 4; j++) acc[i][j] = (f32x4){0.f, 0.f, 0.f, 0.f};
    float rs_unused[4];

    mfma_gemm_dbuf<false>(A, 512, B, 512, 512, row0, col0, smem, acc,
                          rs_unused);

    const int lane = threadIdx.x & 63, wave = threadIdx.x >> 6;
    const int wm = wave >> 1, wn = wave & 1;
    const int er = (lane >> 4) * 4, ec = lane & 15;
#pragma unroll
    for (int tm = 0; tm < 4; tm++)
#pragma unroll
        for (int tn = 0; tn < 4; tn++) {
            int col = col0 + wn * 64 + tn * 16 + ec;
#pragma unroll
            for (int r = 0; r < 4; r++) {
                int row = row0 + wm * 64 + tm * 16 + er + r;
                S[(size_t)row * 2048 + col] = (_Float16)__expf(acc[tm][tn][r]);
            }
        }
}

// ---------------- 4. out = (P.V) * mask / rowsum(P) -------------------------
// 1-D grid 512: batch = bid&7 (XCD pin), col fastest after batch.
__global__ __launch_bounds__(256) void av_mfma(
    const _Float16* __restrict__ Sh, const _Float16* __restrict__ Vt,
    const float* __restrict__ mask, float* __restrict__ out)
{
    __shared__ __align__(16) _Float16 smem[16384];
    __shared__ float l_s[128];
    const int bid = blockIdx.x;
    const int b   = bid & 7;
    const int rem = bid >> 3;
    const int col0 = (rem & 3) * 128;
    const int row0 = (rem >> 2) * 128;

    const _Float16* A = Sh + (size_t)b * 2048 * 2048;
    const _Float16* B = Vt + (size_t)b * 512 * 2048;
    float* O = out + (size_t)b * 2048 * 512;
    const float* mk = mask + (size_t)b * 2048;

    f32x4 acc[4][4];
#pragma unroll
    for (int i = 0; i < 4; i++)
#pragma unroll
        for (int j = 0; j < 4; j++) acc[i][j] = (f32x4){0.f, 0.f, 0.f, 0.f};
    float rs[4] = {0.f, 0.f, 0.f, 0.f};

    mfma_gemm_dbuf<true>(A, 2048, B, 2048, 2048, row0, col0, smem, acc, rs);

    const int lane = threadIdx.x & 63, wave = threadIdx.x >> 6;
    const int wm = wave >> 1, wn = wave & 1;
    const int er = (lane >> 4) * 4, ec = lane & 15;

    // rs[t]: partial rowsum of row (wm*64+t*16+(lane&15)) over this lane's
    // k-quad; butterfly over 4 quads -> full rowsum.
#pragma unroll
    for (int t = 0; t < 4; t++) {
        rs[t] += __shfl_xor(rs[t], 16, 64);
        rs[t] += __shfl_xor(rs[t], 32, 64);
    }
    if (wn == 0 && lane < 16) {
#pragma unroll
        for (int t = 0; t < 4; t++) l_s[wm * 64 + t * 16 + lane] = rs[t];
    }
    __syncthreads();

#pragma unroll
    for (int tm = 0; tm < 4; tm++)
#pragma unroll
        for (int r = 0; r < 4; r++) {
            int lrow = wm * 64 + tm * 16 + er + r;
            int row = row0 + lrow;
            float s = mk[row] / l_s[lrow];
#pragma unroll
            for (int tn = 0; tn < 4; tn++) {
                int col = col0 + wn * 64 + tn * 16 + ec;
                O[(size_t)row * 512 + col] = acc[tm][tn][r] * s;
            }
        }
}

extern "C" void kernel_launch(void* const* d_in, const int* in_sizes, int n_in,
                              void* d_out, int out_size, void* d_ws, size_t ws_size,
                              hipStream_t stream) {
    const float* x    = (const float*)d_in[0];
    const float* mask = (const float*)d_in[1];
    const float* Wq   = (const float*)d_in[2];
    const float* bq   = (const float*)d_in[3];
    const float* Wk   = (const float*)d_in[4];
    const float* bk   = (const float*)d_in[5];
    const float* Wv   = (const float*)d_in[6];
    const float* bv   = (const float*)d_in[7];
    float* out = (float*)d_out;

    const size_t BSD = (size_t)8 * 2048 * 512;       // 8.4M halves
    _Float16* base = (_Float16*)d_ws;
    _Float16* Qh  = base;
    _Float16* Kh  = Qh + BSD;
    _Float16* Vt  = Kh + BSD;                         // [b][d][s]
    _Float16* WqT = Vt + BSD;
    _Float16* WkT = WqT + 512 * 512;
    _Float16* WvT = WkT + 512 * 512;
    _Float16* Xh  = WvT + 512 * 512;
    _Float16* Sh  = Xh;                               // Xh dead after proj

    dim3 blk(256);
    prep<<<dim3(8192 + 3 * 1024), blk, 0, stream>>>(
        x, Wq, Wk, Wv, Xh, WqT, WkT, WvT);
    proj_mfma<<<dim3(128, 4, 3), blk, 0, stream>>>(
        Xh, WqT, bq, WkT, bk, WvT, bv, Qh, Kh, Vt);
    scores_mfma<<<dim3(2048), blk, 0, stream>>>(Qh, Kh, Sh);
    av_mfma<<<dim3(512), blk, 0, stream>>>(Sh, Vt, mask, out);
}